// Round 20
// baseline (2334.283 us; speedup 1.0000x reference)
//
#include <hip/hip_runtime.h>
#include <math.h>

#define B_ 1024
#define T_ 15
#define E_ 128
#define H_ 1024
#define L_ 128
#define V_ 21

typedef unsigned char u8;
typedef long i64;
typedef __attribute__((ext_vector_type(2))) long i64x2;
typedef __attribute__((ext_vector_type(8))) short bf16x8;
typedef __attribute__((ext_vector_type(4))) float f32x4;

__device__ __forceinline__ float sigf(float x) { return 1.0f / (1.0f + __expf(-x)); }
__device__ __forceinline__ float tanhfast(float x) {
    float t = __expf(-2.0f * fabsf(x));
    float r = (1.0f - t) / (1.0f + t);
    return copysignf(r, x);
}

__device__ __forceinline__ ushort f2bf(float f) {
    unsigned u = __float_as_uint(f);
    u += 0x7fffu + ((u >> 16) & 1u);
    return (ushort)(u >> 16);
}
__device__ __forceinline__ float bf2f(ushort u) {
    return __uint_as_float((unsigned)u << 16);
}

// f32 -> OCP e4m3fn, RNE, saturate to 448
__device__ __forceinline__ u8 f2e4(float x) {
    unsigned u = __float_as_uint(x);
    u8 s = (u >> 24) & 0x80;
    float ax = fminf(fabsf(x), 448.0f);
    unsigned ua = __float_as_uint(ax);
    int e = (int)(ua >> 23) - 127;
    if (e < -6) {
        int q = (int)rintf(ax * 512.0f);
        return s | (u8)q;
    }
    unsigned m = ua & 0x7FFFFFu;
    unsigned lsb = (m >> 20) & 1u;
    m += 0x7FFFFu + lsb;
    if (m >> 23) { m = 0; e += 1; }
    if (e > 8) return s | 0x7E;
    return s | (u8)(((e + 7) << 3) | (m >> 20));
}

// Fragment unit (fp8 16x16x32 MFMA, K-tile=64): 1024 B = 16 rows x 64 k.
__device__ __forceinline__ size_t frag_off(int row, int kp) {
    int ch = kp >> 5, q = (kp >> 3) & 3, bb = kp & 7;
    return (size_t)(((q << 4) | (row & 15)) * 16 + ch * 8 + bb);
}

// ========== fp8 64x128 MFMA GEMM, register-direct, RING-6 + XCD swizzle ==========
// R16/R19 structure. NEW: 6 register sets -> prefetch distance ~5 STEPs (~800cy),
// covering the cross-XCD L3 latency of the h operand (written on one XCD per
// column, read by all 8 next step). W stays L2-resident (XCD swizzle). VGPR
// ~206 < 512/wave at 4 waves/SIMD -> no occupancy change.
template <class ALd, class WLd, class Epi>
__global__ __launch_bounds__(256, 4) void gemm_reg(ALd al, WLd wl, Epi ep) {
    const int tid = threadIdx.x;
    const int lane = tid & 63;
    const int w = tid >> 6;
    const int wr = w >> 1, wc = w & 1;

    const int hl = blockIdx.y * gridDim.x + blockIdx.x;
    const int nwg = gridDim.x * gridDim.y;
    int bnb, bmb;
    if ((nwg & 7) == 0) {
        const int per = nwg >> 3;
        const int idx = (hl & 7) * per + (hl >> 3);
        bnb = idx / gridDim.y;
        bmb = idx - bnb * gridDim.y;
    } else {
        bnb = blockIdx.x; bmb = blockIdx.y;
    }
    const int bn = bnb * 128 + al.bn0;
    const int bm = bmb * 64;
    const int nt = al.ntiles(bn);
    const int lb = lane * 16;
    const int rg0 = (bm >> 4) + wr * 2;

    const u8* wbase = wl.base(bm, bn) + (size_t)(wc * 4) * 1024 + lb;

    f32x4 acc[2][4];
#pragma unroll
    for (int m = 0; m < 2; ++m)
#pragma unroll
        for (int n = 0; n < 4; ++n) acc[m][n] = (f32x4)0.0f;

    i64x2 a0[2], a1[2], a2[2], a3[2], a4[2], a5[2];
    i64x2 w0[4], w1[4], w2[4], w3[4], w4[4], w5[4];

    auto LOADA = [&](int t, i64x2* dst) {
        const u8* tb = al.tile(bn, t) + lb;
        dst[0] = *(const i64x2*)(tb + (size_t)rg0 * 1024);
        dst[1] = *(const i64x2*)(tb + (size_t)(rg0 + 1) * 1024);
    };
    auto LOADW = [&](int t, i64x2* dst) {
        const u8* tb = wbase + (size_t)t * 8192;
#pragma unroll
        for (int n = 0; n < 4; ++n) dst[n] = *(const i64x2*)(tb + n * 1024);
    };
    auto STEP = [&](i64x2* a, i64x2* wv) {
#pragma unroll
        for (int m = 0; m < 2; ++m)
#pragma unroll
            for (int n = 0; n < 4; ++n)
                acc[m][n] = __builtin_amdgcn_mfma_f32_16x16x32_fp8_fp8(a[m].x, wv[n].x, acc[m][n], 0, 0, 0);
#pragma unroll
        for (int m = 0; m < 2; ++m)
#pragma unroll
            for (int n = 0; n < 4; ++n)
                acc[m][n] = __builtin_amdgcn_mfma_f32_16x16x32_fp8_fp8(a[m].y, wv[n].y, acc[m][n], 0, 0, 0);
    };

    // prologue: fill all 6 sets (nt >= 16 always)
    LOADA(0, a0); LOADW(0, w0);
    LOADA(1, a1); LOADW(1, w1);
    LOADA(2, a2); LOADW(2, w2);
    LOADA(3, a3); LOADW(3, w3);
    LOADA(4, a4); LOADW(4, w4);
    LOADA(5, a5); LOADW(5, w5);
    int t = 0;
    for (; t + 6 < nt; t += 6) {
        STEP(a0, w0); LOADA(t + 6, a0); LOADW(t + 6, w0);
        STEP(a1, w1); if (t + 7 < nt) { LOADA(t + 7, a1); LOADW(t + 7, w1); }
        STEP(a2, w2); if (t + 8 < nt) { LOADA(t + 8, a2); LOADW(t + 8, w2); }
        STEP(a3, w3); if (t + 9 < nt) { LOADA(t + 9, a3); LOADW(t + 9, w3); }
        STEP(a4, w4); if (t + 10 < nt) { LOADA(t + 10, a4); LOADW(t + 10, w4); }
        STEP(a5, w5); if (t + 11 < nt) { LOADA(t + 11, a5); LOADW(t + 11, w5); }
    }
    const int rem = nt - t;   // 1..6  (18 -> 6, 20 -> 2, 16 -> 4)
    STEP(a0, w0);
    if (rem > 1) STEP(a1, w1);
    if (rem > 2) STEP(a2, w2);
    if (rem > 3) STEP(a3, w3);
    if (rem > 4) STEP(a4, w4);
    if (rem > 5) STEP(a5, w5);
    ep(bm, bn, wr, wc, lane, acc);
}

// ========== bf16 64x128 MFMA GEMM, BK=32 LDS (latent-path GEMMs only) ==========
template <class ALd, class WLd, class Epi>
__global__ __launch_bounds__(256, 4) void gemm_t64(ALd al, WLd wl, Epi ep) {
    __shared__ ushort As[2 * 2048];
    __shared__ ushort Ws[2 * 4096];
    const int tid = threadIdx.x;
    const int lane = tid & 63;
    const int w = tid >> 6;
    const int wr = w >> 1, wc = w & 1;
    const int bn = blockIdx.x * 128;
    const int bm = blockIdx.y * 64;
    const int grow = lane >> 2;
    const int gcol = (lane & 3) * 8;
    const int K = al.K;
    const int nt = K >> 5;

    const ushort* gp[3];
    ushort* ld0[3];
    int lstride[3];
    bool isA[3];
#pragma unroll
    for (int r = 0; r < 3; ++r) {
        const int i = w * 3 + r;
        isA[r] = (i < 4);
        ld0[r] = isA[r] ? (As + i * 512) : (Ws + (i - 4) * 512);
        lstride[r] = isA[r] ? 2048 : 4096;
        gp[r] = isA[r] ? al.addr(bm + i * 16 + grow, gcol)
                       : wl.addr(bn + (i - 4) * 16 + grow, gcol);
    }

    auto STAGE = [&](int buf) {
#pragma unroll
        for (int r = 0; r < 3; ++r) {
            __builtin_amdgcn_global_load_lds(
                (const __attribute__((address_space(1))) void*)gp[r],
                (__attribute__((address_space(3))) void*)(ld0[r] + (buf ? lstride[r] : 0)), 16, 0, 0);
            gp[r] += 32;
        }
    };

    f32x4 acc[2][4];
#pragma unroll
    for (int m = 0; m < 2; ++m)
#pragma unroll
        for (int n = 0; n < 4; ++n) acc[m][n] = (f32x4)0.0f;

    STAGE(0);
    __syncthreads();

    const int frow = lane & 15, fk = (lane >> 4) * 8;
    const int foff = (wr * 32 + frow) * 32 + fk;
    const int goff = (wc * 64 + frow) * 32 + fk;

    for (int t = 0; t < nt; ++t) {
        if (t + 1 < nt) STAGE((t + 1) & 1);
        const ushort* asp = As + (t & 1) * 2048 + foff;
        const ushort* bsp = Ws + (t & 1) * 4096 + goff;
        bf16x8 af[2], bw[4];
#pragma unroll
        for (int m = 0; m < 2; ++m) af[m] = *(const bf16x8*)(asp + m * 512);
#pragma unroll
        for (int n = 0; n < 4; ++n) bw[n] = *(const bf16x8*)(bsp + n * 512);
#pragma unroll
        for (int m = 0; m < 2; ++m)
#pragma unroll
            for (int n = 0; n < 4; ++n)
                acc[m][n] = __builtin_amdgcn_mfma_f32_16x16x32_bf16(af[m], bw[n], acc[m][n], 0, 0, 0);
        __syncthreads();
    }
    ep(bm, bn, wr, wc, lane, acc);
}

// ================= gemm_reg loaders =================
struct AEnc {
    const u8* xef; const u8* hf; int bn0;
    __device__ int ntiles(int) const { return 18; }
    __device__ const u8* tile(int, int t) const {
        return t < 2 ? xef + (size_t)t * 131072 : hf + (size_t)(t - 2) * 131072;
    }
};
struct WEnc {
    const u8* W;
    __device__ const u8* base(int bm, int bn) const {
        return W + ((size_t)(bm >> 10) * 32 + (bn >> 7)) * (18 * 8192);
    }
};
struct ADec {
    const u8* xdf; const u8* hf; const u8* z8f; const u8* h1f; int bn0;
    __device__ int ntiles(int bn) const {
        return bn < 4096 ? 18 : (bn < 5120 ? 20 : 16);
    }
    __device__ const u8* tile(int bn, int t) const {
        if (bn >= 5120) return h1f + (size_t)t * 65536;
        if (t < 2) return xdf + (size_t)t * 65536;
        if (t < 18) return hf + (size_t)(t - 2) * 65536;
        return z8f + (size_t)(t - 18) * 65536;
    }
};
struct WDec {
    const u8* Wg; const u8* W1; const u8* W2;
    __device__ const u8* base(int, int bn) const {
        if (bn < 4096) return Wg + (size_t)(bn >> 7) * (18 * 8192);
        if (bn < 5120) return W1 + (size_t)((bn - 4096) >> 7) * (20 * 8192);
        return W2;
    }
};

// ================= gemm_t64 loaders =================
struct ALdPlain {
    const ushort* A; int ld; int K;
    __device__ const ushort* addr(int row, int k) const { return A + (size_t)row * ld + k; }
};
struct WLdPlain {
    const ushort* W; int ld;
    __device__ const ushort* addr(int n, int k) const { return W + (size_t)n * ld + k; }
};

// ================= epilogues =================
struct EpiEnc8 {
    const float* b_f; const float* b_b; const int* len; int t;
    ushort* c; const u8* hc8; u8* hn8; ushort* hidp;
    __device__ void operator()(int bm, int bn, int wr, int wc, int lane,
                               f32x4 (&acc)[2][4]) const {
        const int j = ((bn >> 6) + wc) * 16 + (lane & 15);
        const int rbase = bm + wr * 32 + ((lane >> 4) << 2);
        const int kt = (j + 128) >> 6;
        const int kp = (j + 128) & 63;
        const size_t fo = frag_off(0, kp);
#pragma unroll
        for (int m = 0; m < 2; ++m) {
#pragma unroll
            for (int r = 0; r < 4; ++r) {
                const int row = rbase + m * 16 + r;
                const int b = row & 1023;
                const int dir = row >> 10;
                const float* bias = dir ? b_b : b_f;
                const int lb = len[b];
                const size_t off = ((size_t)(kt - 2) * 128 + (row >> 4)) * 1024 +
                                   fo + (size_t)(row & 15) * 16;
                if (t < lb) {
                    float gi = acc[m][0][r] + bias[j];
                    float gf = acc[m][1][r] + bias[1024 + j];
                    float gg = acc[m][2][r] + bias[2048 + j];
                    float go = acc[m][3][r] + bias[3072 + j];
                    const size_t o = (size_t)row * 1024 + j;
                    float nc = sigf(gf) * bf2f(c[o]) + sigf(gi) * tanhfast(gg);
                    c[o] = f2bf(nc);
                    float nh = sigf(go) * tanhfast(nc);
                    hn8[off] = f2e4(nh);
                    if (t == lb - 1)
                        hidp[(size_t)b * 2048 + dir * 1024 + j] = f2bf(nh);
                } else {
                    hn8[off] = hc8[off];
                }
            }
        }
    }
};

struct EpiDec8 {
    const float *bi, *bo, *bfv, *bg, *b1, *b2;
    ushort* c; u8* hn8; u8* hid1cur;
    const int* tokens; const int* len; int t;
    float* accs;
    __device__ void operator()(int bm, int bn, int wr, int wc, int lane,
                               f32x4 (&acc)[2][4]) const {
        const int rbase = bm + wr * 32 + ((lane >> 4) << 2);
        if (bn < 4096) {
            const int j = ((bn >> 6) + wc) * 16 + (lane & 15);
            const int kt = (j + 128) >> 6;
            const int kp = (j + 128) & 63;
            const size_t fo = frag_off(0, kp);
#pragma unroll
            for (int m = 0; m < 2; ++m) {
#pragma unroll
                for (int r = 0; r < 4; ++r) {
                    const int b = rbase + m * 16 + r;
                    const size_t o = (size_t)b * 1024 + j;
                    float gi = sigf(acc[m][0][r] + bi[j]);
                    float go = sigf(acc[m][1][r] + bo[j]);
                    float gf = sigf(acc[m][2][r] + bfv[j]);
                    float gg = tanhfast(acc[m][3][r] + bg[j]);
                    float nc = gf * bf2f(c[o]) + gi * gg;
                    c[o] = f2bf(nc);
                    const size_t off = ((size_t)(kt - 2) * 64 + (b >> 4)) * 1024 +
                                       fo + (size_t)(b & 15) * 16;
                    hn8[off] = f2e4(go * tanhfast(nc));
                }
            }
        } else if (bn < 5120) {
            const int cb = (bn - 4096) + wc * 64;
#pragma unroll
            for (int m = 0; m < 2; ++m)
#pragma unroll
                for (int n = 0; n < 4; ++n) {
                    const int col = cb + n * 16 + (lane & 15);
                    const int kt = col >> 6;
                    const size_t fo = frag_off(0, col & 63);
#pragma unroll
                    for (int r = 0; r < 4; ++r) {
                        const int row = rbase + m * 16 + r;
                        const size_t off = ((size_t)kt * 64 + (row >> 4)) * 1024 +
                                           fo + (size_t)(row & 15) * 16;
                        hid1cur[off] = f2e4(fmaxf(acc[m][n][r] + b1[col], 0.0f));
                    }
                }
        } else {
            if (wc != 0) return;
            const int ts = t - 1;
            const int col0 = lane & 15;
            const bool v1ok = col0 < (V_ - 16);
            const float b2v0 = b2[col0];
            const float b2v1 = v1ok ? b2[16 + col0] : 0.0f;
            float ce_loc = 0.f, cor_loc = 0.f, msk_loc = 0.f;
#pragma unroll
            for (int m = 0; m < 2; ++m) {
#pragma unroll
                for (int r = 0; r < 4; ++r) {
                    const int b = rbase + m * 16 + r;
                    const int lb = len[b];
                    float v0 = acc[m][0][r] + b2v0;
                    float v1 = v1ok ? (acc[m][1][r] + b2v1) : -1e30f;
                    float mv; int mi;
                    if (v1 > v0) { mv = v1; mi = 16 + col0; } else { mv = v0; mi = col0; }
#pragma unroll
                    for (int s = 1; s < 16; s <<= 1) {
                        float ov = __shfl_xor(mv, s);
                        int oi = __shfl_xor(mi, s);
                        if (ov > mv || (ov == mv && oi < mi)) { mv = ov; mi = oi; }
                    }
                    float se = expf(v0 - mv) + (v1ok ? expf(v1 - mv) : 0.0f);
#pragma unroll
                    for (int s = 1; s < 16; s <<= 1) se += __shfl_xor(se, s);
                    float lse = mv + logf(se);
                    int tgt = (ts < lb) ? tokens[b * T_ + ts] : 0;
                    int srcl = (lane & 48) | (tgt & 15);
                    float sv0 = __shfl(v0, srcl);
                    float sv1 = __shfl(v1, srcl);
                    float stgt = (tgt < 16) ? sv0 : sv1;
                    if (ts <= lb && col0 == 0) {
                        ce_loc += lse - stgt;
                        cor_loc += (mi == tgt) ? 1.0f : 0.0f;
                        msk_loc += 1.0f;
                    }
                }
            }
            float ce = __shfl(ce_loc, 0) + __shfl(ce_loc, 16) + __shfl(ce_loc, 32) + __shfl(ce_loc, 48);
            float co = __shfl(cor_loc, 0) + __shfl(cor_loc, 16) + __shfl(cor_loc, 32) + __shfl(cor_loc, 48);
            float mk = __shfl(msk_loc, 0) + __shfl(msk_loc, 16) + __shfl(msk_loc, 32) + __shfl(msk_loc, 48);
            if (lane == 0) {
                atomicAdd(&accs[0], ce);
                atomicAdd(&accs[1], co);
                atomicAdd(&accs[2], mk);
            }
        }
    }
};

struct EpiStoreF32 {
    float* out; int ldc;
    __device__ void operator()(int bm, int bn, int wr, int wc, int lane,
                               f32x4 (&acc)[2][4]) const {
        const int rbase = bm + wr * 32 + ((lane >> 4) << 2);
        const int cbase = bn + wc * 64 + (lane & 15);
#pragma unroll
        for (int m = 0; m < 2; ++m)
#pragma unroll
            for (int n = 0; n < 4; ++n)
#pragma unroll
                for (int r = 0; r < 4; ++r)
                    out[(size_t)(rbase + m * 16 + r) * ldc + cbase + n * 16] = acc[m][n][r];
    }
};
struct EpiBiasF8Frag {
    u8* out; const float* bias;
    __device__ void operator()(int bm, int bn, int wr, int wc, int lane,
                               f32x4 (&acc)[2][4]) const {
        const int rbase = bm + wr * 32 + ((lane >> 4) << 2);
        const int cbase = bn + wc * 64 + (lane & 15);
#pragma unroll
        for (int m = 0; m < 2; ++m)
#pragma unroll
            for (int n = 0; n < 4; ++n) {
                const int col = cbase + n * 16;
                const int kt = (col + 128) >> 6;
                const size_t fo = frag_off(0, col & 63);
#pragma unroll
                for (int r = 0; r < 4; ++r) {
                    const int row = rbase + m * 16 + r;
                    const size_t off = ((size_t)(kt - 2) * 64 + (row >> 4)) * 1024 +
                                       fo + (size_t)(row & 15) * 16;
                    out[off] = f2e4(acc[m][n][r] + bias[col]);
                }
            }
    }
};

// ================= MEGA-PACK: all prep work in ONE launch =================
struct PackP {
    const float *x_enc, *emb, *Wih_f, *Whh_f, *Wih_b, *Whh_b;
    const float *Wi, *Wo, *Wf, *Wg, *W1, *W2, *Wm, *Wl, *Wz;
    const int *tokens, *len;
    ushort *cenc, *cdec, *Wml, *Wzp;
    u8 *hfA, *xef, *xdf, *WfE, *WfDg, *WfD1, *WfD2;
    float* accs;
};

__global__ __launch_bounds__(256) void mega_pack(PackP P) {
    const int blk = blockIdx.x;
    const int tid = threadIdx.x;

    if (blk < 8192) {                                   // init_zero
        int i = blk * 256 + tid;
        if (i < 2 * 1024 * 1024) { P.cenc[i] = 0; P.hfA[i] = 0; }
        if (i < 1024 * 1024) P.cdec[i] = 0;
        if (i < 8) P.accs[i] = 0.0f;
        return;
    }
    if (blk < 17408) {                                  // pack_wenc_frag
        int i = (blk - 8192) * 256 + tid;
        int b0 = (i & 3) * 4;
        int lane = (i >> 2) & 63;
        int unit = i >> 8;
        int sub = unit & 7;
        int ktb = unit >> 3;
        int kt = ktb % 18;
        int blk2 = ktb / 18;
        int bnb = blk2 & 31, dir = blk2 >> 5;
        int col = bnb * 128 + (sub >> 2) * 64 + (sub & 3) * 16 + (lane & 15);
        int j = ((col >> 6) << 4) + (col & 15);
        int g = (col >> 4) & 3;
        int srow = g * 1024 + j;
        int k = kt * 64 + (b0 >> 3) * 32 + (lane >> 4) * 8 + (b0 & 7);
        float4 v;
        if (k < 128) {
            const float* s = dir ? P.Wih_b : P.Wih_f;
            v = *(const float4*)(s + (size_t)srow * 128 + k);
        } else {
            const float* s = dir ? P.Whh_b : P.Whh_f;
            v = *(const float4*)(s + (size_t)srow * 1024 + (k - 128));
        }
        unsigned o = f2e4(v.x) | ((unsigned)f2e4(v.y) << 8) |
                     ((unsigned)f2e4(v.z) << 16) | ((unsigned)f2e4(v.w) << 24);
        *(unsigned*)(P.WfE + (size_t)unit * 1024 + lane * 16 + b0) = o;
        return;
    }
    if (blk < 22016) {                                  // pack_wdec_frag
        int i = (blk - 17408) * 256 + tid;
        int b0 = (i & 3) * 4;
        int lane = (i >> 2) & 63;
        int unit = i >> 8;
        int sub = unit & 7;
        int ktb = unit >> 3;
        int kt = ktb % 18;
        int bnb = ktb / 18;
        int col = bnb * 128 + (sub >> 2) * 64 + (sub & 3) * 16 + (lane & 15);
        int j = ((col >> 6) << 4) + (col & 15);
        int g = (col >> 4) & 3;
        const float* s = (g == 0) ? P.Wi : (g == 1) ? P.Wo : (g == 2) ? P.Wf : P.Wg;
        int k = kt * 64 + (b0 >> 3) * 32 + (lane >> 4) * 8 + (b0 & 7);
        float4 v = *(const float4*)(s + (size_t)j * 1152 + k);
        unsigned o = f2e4(v.x) | ((unsigned)f2e4(v.y) << 8) |
                     ((unsigned)f2e4(v.z) << 16) | ((unsigned)f2e4(v.w) << 24);
        *(unsigned*)(P.WfDg + (size_t)unit * 1024 + lane * 16 + b0) = o;
        return;
    }
    if (blk < 23296) {                                  // pack_w1_frag
        int i = (blk - 22016) * 256 + tid;
        int b0 = (i & 3) * 4;
        int lane = (i >> 2) & 63;
        int unit = i >> 8;
        int sub = unit & 7;
        int ktb = unit >> 3;
        int kt = ktb % 20;
        int bnb = ktb / 20;
        int col = bnb * 128 + (sub >> 2) * 64 + (sub & 3) * 16 + (lane & 15);
        int k = kt * 64 + (b0 >> 3) * 32 + (lane >> 4) * 8 + (b0 & 7);
        float4 v = *(const float4*)(P.W1 + (size_t)col * 1280 + k);
        unsigned o = f2e4(v.x) | ((unsigned)f2e4(v.y) << 8) |
                     ((unsigned)f2e4(v.z) << 16) | ((unsigned)f2e4(v.w) << 24);
        *(unsigned*)(P.WfD1 + (size_t)unit * 1024 + lane * 16 + b0) = o;
        return;
    }
    if (blk < 23424) {                                  // pack_w2_frag
        int i = (blk - 23296) * 256 + tid;
        int b0 = (i & 3) * 4;
        int lane = (i >> 2) & 63;
        int unit = i >> 8;
        int sub = unit & 7;
        int kt = unit >> 3;
        int col = (sub >> 2) * 64 + (sub & 3) * 16 + (lane & 15);
        unsigned o = 0;
        if (col < V_) {
            int k = kt * 64 + (b0 >> 3) * 32 + (lane >> 4) * 8 + (b0 & 7);
            float4 v = *(const float4*)(P.W2 + (size_t)col * 1024 + k);
            o = f2e4(v.x) | ((unsigned)f2e4(v.y) << 8) |
                ((unsigned)f2e4(v.z) << 16) | ((unsigned)f2e4(v.w) << 24);
        }
        *(unsigned*)(P.WfD2 + (size_t)unit * 1024 + lane * 16 + b0) = o;
        return;
    }
    if (blk < 23680) {                                  // pack_cols Wm
        int i = (blk - 23424) * 256 + tid;
        int r = i >> 9, c4 = (i & 511) * 4;
        float4 v = *(const float4*)(P.Wm + (size_t)r * 2048 + c4);
        ushort4 o = { f2bf(v.x), f2bf(v.y), f2bf(v.z), f2bf(v.w) };
        *(ushort4*)(P.Wml + (size_t)r * 2048 + c4) = o;
        return;
    }
    if (blk < 23936) {                                  // pack_cols Wl
        int i = (blk - 23680) * 256 + tid;
        int r = i >> 9, c4 = (i & 511) * 4;
        float4 v = *(const float4*)(P.Wl + (size_t)r * 2048 + c4);
        ushort4 o = { f2bf(v.x), f2bf(v.y), f2bf(v.z), f2bf(v.w) };
        *(ushort4*)(P.Wml + (size_t)(r + 128) * 2048 + c4) = o;
        return;
    }
    if (blk < 24064) {                                  // pack_cols Wz
        int i = (blk - 23936) * 256 + tid;
        int r = i >> 5, c4 = (i & 31) * 4;
        float4 v = *(const float4*)(P.Wz + (size_t)r * 128 + c4);
        ushort4 o = { f2bf(v.x), f2bf(v.y), f2bf(v.z), f2bf(v.w) };
        *(ushort4*)(P.Wzp + (size_t)r * 128 + c4) = o;
        return;
    }
    if (blk < 27904) {                                  // pack_xenc_frag
        int i = (blk - 24064) * 256 + tid;
        int b0 = (i & 3) * 4;
        int lane = (i >> 2) & 63;
        int unit = i >> 8;
        int rg = unit & 127;
        int tk = unit >> 7;
        int kt = tk & 1, t = tk >> 1;
        int row = rg * 16 + (lane & 15);
        int k = kt * 64 + (b0 >> 3) * 32 + (lane >> 4) * 8 + (b0 & 7);
        int dir = row >> 10, bidx = row & 1023;
        int tt = t;
        if (dir) { int ri = P.len[bidx] - 1 - t; tt = ri < 0 ? 0 : (ri > T_ - 1 ? T_ - 1 : ri); }
        float4 v = *(const float4*)(P.x_enc + ((size_t)bidx * T_ + tt) * 128 + k);
        unsigned o = f2e4(v.x) | ((unsigned)f2e4(v.y) << 8) |
                     ((unsigned)f2e4(v.z) << 16) | ((unsigned)f2e4(v.w) << 24);
        *(unsigned*)(P.xef + (size_t)unit * 1024 + lane * 16 + b0) = o;
        return;
    }
    {                                                   // pack_xdec_frag
        int i = (blk - 27904) * 256 + tid;
        int b0 = (i & 3) * 4;
        int lane = (i >> 2) & 63;
        int unit = i >> 8;
        int rg = unit & 63;
        int tk = unit >> 6;
        int kt = tk & 1, t = tk >> 1;
        unsigned o = 0;
        if (t > 0) {
            int row = rg * 16 + (lane & 15);
            int k = kt * 64 + (b0 >> 3) * 32 + (lane >> 4) * 8 + (b0 & 7);
            int tok = P.tokens[(size_t)row * T_ + (t - 1)];
            float4 v = *(const float4*)(P.emb + (size_t)tok * 128 + k);
            o = f2e4(v.x) | ((unsigned)f2e4(v.y) << 8) |
                ((unsigned)f2e4(v.z) << 16) | ((unsigned)f2e4(v.w) << 24);
        }
        *(unsigned*)(P.xdf + (size_t)unit * 1024 + lane * 16 + b0) = o;
    }
}

// ================= elementwise =================
__global__ void latent_ew(const float* __restrict__ ml, const float* __restrict__ bmv,
                          const float* __restrict__ blv, const float* __restrict__ eps,
                          ushort* __restrict__ zb, u8* __restrict__ z8f,
                          float* __restrict__ klacc) {
    int idx = blockIdx.x * 256 + threadIdx.x;
    int b = idx >> 7, l = idx & (L_ - 1);
    float mean = ml[(size_t)b * 256 + l] + bmv[l];
    float logv = ml[(size_t)b * 256 + L_ + l] + blv[l];
    float zv = eps[idx] * expf(0.5f * logv) + mean;
    zb[idx] = f2bf(zv);
    size_t off = ((size_t)(l >> 6) * 64 + (b >> 4)) * 1024 +
                 frag_off(0, l & 63) + (size_t)(b & 15) * 16;
    z8f[off] = f2e4(zv);
    float part = 1.0f + logv - mean * mean - expf(logv);
    for (int offc = 32; offc; offc >>= 1) part += __shfl_down(part, offc);
    __shared__ float s[4];
    int lane = threadIdx.x & 63, wv = threadIdx.x >> 6;
    if (lane == 0) s[wv] = part;
    __syncthreads();
    if (threadIdx.x == 0) atomicAdd(klacc, s[0] + s[1] + s[2] + s[3]);
}

__global__ void finalize_k(const float* accs, float* out) {
    if (threadIdx.x == 0 && blockIdx.x == 0) {
        float kl = -0.5f * accs[3] / (float)B_;
        float amino = accs[0] / (float)B_;
        out[0] = amino + 0.1f * kl;
        out[1] = amino;
        out[2] = kl;
        out[3] = accs[1] / accs[2];
    }
}

// ================= host =================
extern "C" void kernel_launch(void* const* d_in, const int* in_sizes, int n_in,
                              void* d_out, int out_size, void* d_ws, size_t ws_size,
                              hipStream_t stream) {
    (void)in_sizes; (void)n_in; (void)out_size; (void)ws_size;
    const float* x_enc  = (const float*)d_in[0];
    const int*   tokens = (const int*)d_in[1];
    const int*   lengths= (const int*)d_in[2];
    const float* eps    = (const float*)d_in[3];
    const float* emb    = (const float*)d_in[4];
    const float* Wih_f  = (const float*)d_in[5];
    const float* Whh_f  = (const float*)d_in[6];
    const float* b_f    = (const float*)d_in[7];
    const float* Wih_b  = (const float*)d_in[8];
    const float* Whh_b  = (const float*)d_in[9];
    const float* b_b    = (const float*)d_in[10];
    const float* Wm     = (const float*)d_in[11];
    const float* bm     = (const float*)d_in[12];
    const float* Wl     = (const float*)d_in[13];
    const float* bl     = (const float*)d_in[14];
    const float* Wz     = (const float*)d_in[15];
    const float* bz     = (const float*)d_in[16];
    const float* Wi     = (const float*)d_in[17];
    const float* bi     = (const float*)d_in[18];
    const float* Wo     = (const float*)d_in[19];
    const float* bo     = (const float*)d_in[20];
    const float* Wfm    = (const float*)d_in[21];
    const float* bf     = (const float*)d_in[22];
    const float* Wg     = (const float*)d_in[23];
    const float* bg     = (const float*)d_in[24];
    const float* W1     = (const float*)d_in[25];
    const float* b1     = (const float*)d_in[26];
    const float* W2     = (const float*)d_in[27];
    const float* b2     = (const float*)d_in[28];

    float*  ml   = (float*)d_ws;
    float*  accs = ml + 262144;
    ushort* cenc = (ushort*)(accs + 64);
    ushort* cdec = cenc + 2 * 1024 * 1024;
    ushort* hidp = cdec + 1024 * 1024;
    ushort* Wml  = hidp + 2 * 1024 * 1024;
    ushort* Wzp  = Wml + 256 * 2048;
    ushort* zb   = Wzp + 1024 * 128;
    u8* xef  = (u8*)(zb + 1024 * 128);
    u8* hfA  = xef + 15 * 2 * 128 * 1024;
    u8* hfB  = hfA + 16 * 128 * 1024;
    u8* xdf  = hfB + 16 * 128 * 1024;
    u8* hdfA = xdf + 15 * 2 * 64 * 1024;
    u8* hdfB = hdfA + 16 * 64 * 1024;
    u8* z8f  = hdfB + 16 * 64 * 1024;
    u8* h1fA = z8f + 2 * 64 * 1024;
    u8* h1fB = h1fA + 16 * 64 * 1024;
    u8* WfE  = h1fB + 16 * 64 * 1024;
    u8* WfDg = WfE + 2 * 32 * 18 * 8 * 1024;
    u8* WfD1 = WfDg + 32 * 18 * 8 * 1024;
    u8* WfD2 = WfD1 + 8 * 20 * 8 * 1024;

    // ---- ALL prep in one launch ----
    {
        PackP p{ x_enc, emb, Wih_f, Whh_f, Wih_b, Whh_b,
                 Wi, Wo, Wfm, Wg, W1, W2, Wm, Wl, Wz,
                 tokens, lengths,
                 cenc, cdec, Wml, Wzp,
                 hfA, xef, xdf, WfE, WfDg, WfD1, WfD2, accs };
        mega_pack<<<29824, 256, 0, stream>>>(p);
    }

    // ---- encoder: fp8 reg-direct 64x128 ring-6 + XCD swizzle ----
    {
        const u8* hc = hfA; u8* hn = hfB;
        for (int t = 0; t < T_; ++t) {
            gemm_reg<<<dim3(32, 32), 256, 0, stream>>>(
                AEnc{ xef + (size_t)t * 2 * 131072, hc, 0 }, WEnc{ WfE },
                EpiEnc8{ b_f, b_b, lengths, t, cenc, hc, hn, hidp });
            const u8* tmp = hn; hn = (u8*)hc; hc = tmp;
        }
    }
    // ---- latents (bf16 LDS path) ----
    gemm_t64<<<dim3(2, 16), 256, 0, stream>>>(
        ALdPlain{ hidp, 2048, 2048 }, WLdPlain{ Wml, 2048 }, EpiStoreF32{ ml, 256 });
    latent_ew<<<512, 256, 0, stream>>>(ml, bm, bl, eps, zb, z8f, &accs[3]);
    gemm_t64<<<dim3(8, 16), 256, 0, stream>>>(
        ALdPlain{ zb, 128, 128 }, WLdPlain{ Wzp, 128 }, EpiBiasF8Frag{ hdfA, bz });

    // ---- decoder: fp8 reg-direct 64x128 ring-6 + XCD swizzle ----
    {
        const u8* dc = hdfA; u8* dn = hdfB;
        for (int t = 0; t < T_; ++t) {
            u8* h1c = (t & 1) ? h1fB : h1fA;
            const u8* h1p = (t & 1) ? h1fA : h1fB;
            dim3 grid(t == 0 ? 40 : 41, 16);
            gemm_reg<<<grid, 256, 0, stream>>>(
                ADec{ xdf + (size_t)t * 2 * 65536, dc, z8f, h1p, 0 },
                WDec{ WfDg, WfD1, WfD2 },
                EpiDec8{ bi, bo, bf, bg, b1, b2, cdec, dn, h1c, tokens, lengths, t, accs });
            const u8* tmp = dn; dn = (u8*)dc; dc = tmp;
        }
        gemm_reg<<<dim3(1, 16), 256, 0, stream>>>(
            ADec{ xdf, dc, z8f, h1fA, 5120 },
            WDec{ WfDg, WfD1, WfD2 },
            EpiDec8{ bi, bo, bf, bg, b1, b2, cdec, hdfB, h1fB, tokens, lengths, T_, accs });
    }

    finalize_k<<<1, 64, 0, stream>>>(accs, (float*)d_out);
}

// Round 21
// 772.559 us; speedup vs baseline: 3.0215x; 3.0215x over previous
//
#include <hip/hip_runtime.h>
#include <math.h>

#define B_ 1024
#define T_ 15
#define E_ 128
#define H_ 1024
#define L_ 128
#define V_ 21

typedef unsigned char u8;
typedef long i64;
typedef __attribute__((ext_vector_type(2))) long i64x2;
typedef __attribute__((ext_vector_type(8))) short bf16x8;
typedef __attribute__((ext_vector_type(4))) float f32x4;

__device__ __forceinline__ float sigf(float x) { return 1.0f / (1.0f + __expf(-x)); }
__device__ __forceinline__ float tanhfast(float x) {
    float t = __expf(-2.0f * fabsf(x));
    float r = (1.0f - t) / (1.0f + t);
    return copysignf(r, x);
}

__device__ __forceinline__ ushort f2bf(float f) {
    unsigned u = __float_as_uint(f);
    u += 0x7fffu + ((u >> 16) & 1u);
    return (ushort)(u >> 16);
}
__device__ __forceinline__ float bf2f(ushort u) {
    return __uint_as_float((unsigned)u << 16);
}

// f32 -> OCP e4m3fn, RNE, saturate to 448
__device__ __forceinline__ u8 f2e4(float x) {
    unsigned u = __float_as_uint(x);
    u8 s = (u >> 24) & 0x80;
    float ax = fminf(fabsf(x), 448.0f);
    unsigned ua = __float_as_uint(ax);
    int e = (int)(ua >> 23) - 127;
    if (e < -6) {
        int q = (int)rintf(ax * 512.0f);
        return s | (u8)q;
    }
    unsigned m = ua & 0x7FFFFFu;
    unsigned lsb = (m >> 20) & 1u;
    m += 0x7FFFFu + lsb;
    if (m >> 23) { m = 0; e += 1; }
    if (e > 8) return s | 0x7E;
    return s | (u8)(((e + 7) << 3) | (m >> 20));
}

// Fragment unit (fp8 16x16x32 MFMA, K-tile=64): 1024 B = 16 rows x 64 k.
__device__ __forceinline__ size_t frag_off(int row, int kp) {
    int ch = kp >> 5, q = (kp >> 3) & 3, bb = kp & 7;
    return (size_t)(((q << 4) | (row & 15)) * 16 + ch * 8 + bb);
}

// ========== fp8 64x128 MFMA GEMM, register-direct, RING-3 + XCD swizzle ==========
// R19 (proven 773us). Ring-3 is the VGPR-allocator sweet spot: R20's ring-6
// spilled to scratch (VGPR capped at 64, 185MB scratch writes, 3x regression).
template <class ALd, class WLd, class Epi>
__global__ __launch_bounds__(256, 4) void gemm_reg(ALd al, WLd wl, Epi ep) {
    const int tid = threadIdx.x;
    const int lane = tid & 63;
    const int w = tid >> 6;
    const int wr = w >> 1, wc = w & 1;

    const int hl = blockIdx.y * gridDim.x + blockIdx.x;
    const int nwg = gridDim.x * gridDim.y;
    int bnb, bmb;
    if ((nwg & 7) == 0) {
        const int per = nwg >> 3;
        const int idx = (hl & 7) * per + (hl >> 3);
        bnb = idx / gridDim.y;
        bmb = idx - bnb * gridDim.y;
    } else {
        bnb = blockIdx.x; bmb = blockIdx.y;
    }
    const int bn = bnb * 128 + al.bn0;
    const int bm = bmb * 64;
    const int nt = al.ntiles(bn);
    const int lb = lane * 16;
    const int rg0 = (bm >> 4) + wr * 2;

    const u8* wbase = wl.base(bm, bn) + (size_t)(wc * 4) * 1024 + lb;

    f32x4 acc[2][4];
#pragma unroll
    for (int m = 0; m < 2; ++m)
#pragma unroll
        for (int n = 0; n < 4; ++n) acc[m][n] = (f32x4)0.0f;

    i64x2 a0[2], a1[2], a2[2], w0[4], w1[4], w2[4];

    auto LOADA = [&](int t, i64x2* dst) {
        const u8* tb = al.tile(bn, t) + lb;
        dst[0] = *(const i64x2*)(tb + (size_t)rg0 * 1024);
        dst[1] = *(const i64x2*)(tb + (size_t)(rg0 + 1) * 1024);
    };
    auto LOADW = [&](int t, i64x2* dst) {
        const u8* tb = wbase + (size_t)t * 8192;
#pragma unroll
        for (int n = 0; n < 4; ++n) dst[n] = *(const i64x2*)(tb + n * 1024);
    };
    auto STEP = [&](i64x2* a, i64x2* wv) {
#pragma unroll
        for (int m = 0; m < 2; ++m)
#pragma unroll
            for (int n = 0; n < 4; ++n)
                acc[m][n] = __builtin_amdgcn_mfma_f32_16x16x32_fp8_fp8(a[m].x, wv[n].x, acc[m][n], 0, 0, 0);
#pragma unroll
        for (int m = 0; m < 2; ++m)
#pragma unroll
            for (int n = 0; n < 4; ++n)
                acc[m][n] = __builtin_amdgcn_mfma_f32_16x16x32_fp8_fp8(a[m].y, wv[n].y, acc[m][n], 0, 0, 0);
    };

    LOADA(0, a0); LOADW(0, w0);
    LOADA(1, a1); LOADW(1, w1);
    LOADA(2, a2); LOADW(2, w2);
    int t = 0;
    for (; t + 3 < nt; t += 3) {
        STEP(a0, w0); LOADA(t + 3, a0); LOADW(t + 3, w0);
        STEP(a1, w1); if (t + 4 < nt) { LOADA(t + 4, a1); LOADW(t + 4, w1); }
        STEP(a2, w2); if (t + 5 < nt) { LOADA(t + 5, a2); LOADW(t + 5, w2); }
    }
    const int rem = nt - t;   // 1..3
    STEP(a0, w0);
    if (rem > 1) STEP(a1, w1);
    if (rem > 2) STEP(a2, w2);
    ep(bm, bn, wr, wc, lane, acc);
}

// ========== bf16 64x128 MFMA GEMM, BK=32 LDS (latent-path GEMMs only) ==========
template <class ALd, class WLd, class Epi>
__global__ __launch_bounds__(256, 4) void gemm_t64(ALd al, WLd wl, Epi ep) {
    __shared__ ushort As[2 * 2048];
    __shared__ ushort Ws[2 * 4096];
    const int tid = threadIdx.x;
    const int lane = tid & 63;
    const int w = tid >> 6;
    const int wr = w >> 1, wc = w & 1;
    const int bn = blockIdx.x * 128;
    const int bm = blockIdx.y * 64;
    const int grow = lane >> 2;
    const int gcol = (lane & 3) * 8;
    const int K = al.K;
    const int nt = K >> 5;

    const ushort* gp[3];
    ushort* ld0[3];
    int lstride[3];
    bool isA[3];
#pragma unroll
    for (int r = 0; r < 3; ++r) {
        const int i = w * 3 + r;
        isA[r] = (i < 4);
        ld0[r] = isA[r] ? (As + i * 512) : (Ws + (i - 4) * 512);
        lstride[r] = isA[r] ? 2048 : 4096;
        gp[r] = isA[r] ? al.addr(bm + i * 16 + grow, gcol)
                       : wl.addr(bn + (i - 4) * 16 + grow, gcol);
    }

    auto STAGE = [&](int buf) {
#pragma unroll
        for (int r = 0; r < 3; ++r) {
            __builtin_amdgcn_global_load_lds(
                (const __attribute__((address_space(1))) void*)gp[r],
                (__attribute__((address_space(3))) void*)(ld0[r] + (buf ? lstride[r] : 0)), 16, 0, 0);
            gp[r] += 32;
        }
    };

    f32x4 acc[2][4];
#pragma unroll
    for (int m = 0; m < 2; ++m)
#pragma unroll
        for (int n = 0; n < 4; ++n) acc[m][n] = (f32x4)0.0f;

    STAGE(0);
    __syncthreads();

    const int frow = lane & 15, fk = (lane >> 4) * 8;
    const int foff = (wr * 32 + frow) * 32 + fk;
    const int goff = (wc * 64 + frow) * 32 + fk;

    for (int t = 0; t < nt; ++t) {
        if (t + 1 < nt) STAGE((t + 1) & 1);
        const ushort* asp = As + (t & 1) * 2048 + foff;
        const ushort* bsp = Ws + (t & 1) * 4096 + goff;
        bf16x8 af[2], bw[4];
#pragma unroll
        for (int m = 0; m < 2; ++m) af[m] = *(const bf16x8*)(asp + m * 512);
#pragma unroll
        for (int n = 0; n < 4; ++n) bw[n] = *(const bf16x8*)(bsp + n * 512);
#pragma unroll
        for (int m = 0; m < 2; ++m)
#pragma unroll
            for (int n = 0; n < 4; ++n)
                acc[m][n] = __builtin_amdgcn_mfma_f32_16x16x32_bf16(af[m], bw[n], acc[m][n], 0, 0, 0);
        __syncthreads();
    }
    ep(bm, bn, wr, wc, lane, acc);
}

// ================= gemm_reg loaders =================
struct AEnc {
    const u8* xef; const u8* hf; int bn0;
    __device__ int ntiles(int) const { return 18; }
    __device__ const u8* tile(int, int t) const {
        return t < 2 ? xef + (size_t)t * 131072 : hf + (size_t)(t - 2) * 131072;
    }
};
struct WEnc {
    const u8* W;
    __device__ const u8* base(int bm, int bn) const {
        return W + ((size_t)(bm >> 10) * 32 + (bn >> 7)) * (18 * 8192);
    }
};
struct ADec {
    const u8* xdf; const u8* hf; const u8* z8f; const u8* h1f; int bn0;
    __device__ int ntiles(int bn) const {
        return bn < 4096 ? 18 : (bn < 5120 ? 20 : 16);
    }
    __device__ const u8* tile(int bn, int t) const {
        if (bn >= 5120) return h1f + (size_t)t * 65536;
        if (t < 2) return xdf + (size_t)t * 65536;
        if (t < 18) return hf + (size_t)(t - 2) * 65536;
        return z8f + (size_t)(t - 18) * 65536;
    }
};
struct WDec {
    const u8* Wg; const u8* W1; const u8* W2;
    __device__ const u8* base(int, int bn) const {
        if (bn < 4096) return Wg + (size_t)(bn >> 7) * (18 * 8192);
        if (bn < 5120) return W1 + (size_t)((bn - 4096) >> 7) * (20 * 8192);
        return W2;
    }
};

// ================= gemm_t64 loaders =================
struct ALdPlain {
    const ushort* A; int ld; int K;
    __device__ const ushort* addr(int row, int k) const { return A + (size_t)row * ld + k; }
};
struct WLdPlain {
    const ushort* W; int ld;
    __device__ const ushort* addr(int n, int k) const { return W + (size_t)n * ld + k; }
};

// ================= epilogues =================
struct EpiEnc8 {
    const float* b_f; const float* b_b; const int* len; int t;
    ushort* c; const u8* hc8; u8* hn8; ushort* hidp;
    __device__ void operator()(int bm, int bn, int wr, int wc, int lane,
                               f32x4 (&acc)[2][4]) const {
        const int j = ((bn >> 6) + wc) * 16 + (lane & 15);
        const int rbase = bm + wr * 32 + ((lane >> 4) << 2);
        const int kt = (j + 128) >> 6;
        const int kp = (j + 128) & 63;
        const size_t fo = frag_off(0, kp);
#pragma unroll
        for (int m = 0; m < 2; ++m) {
#pragma unroll
            for (int r = 0; r < 4; ++r) {
                const int row = rbase + m * 16 + r;
                const int b = row & 1023;
                const int dir = row >> 10;
                const float* bias = dir ? b_b : b_f;
                const int lb = len[b];
                const size_t off = ((size_t)(kt - 2) * 128 + (row >> 4)) * 1024 +
                                   fo + (size_t)(row & 15) * 16;
                if (t < lb) {
                    float gi = acc[m][0][r] + bias[j];
                    float gf = acc[m][1][r] + bias[1024 + j];
                    float gg = acc[m][2][r] + bias[2048 + j];
                    float go = acc[m][3][r] + bias[3072 + j];
                    const size_t o = (size_t)row * 1024 + j;
                    float nc = sigf(gf) * bf2f(c[o]) + sigf(gi) * tanhfast(gg);
                    c[o] = f2bf(nc);
                    float nh = sigf(go) * tanhfast(nc);
                    hn8[off] = f2e4(nh);
                    if (t == lb - 1)
                        hidp[(size_t)b * 2048 + dir * 1024 + j] = f2bf(nh);
                } else {
                    hn8[off] = hc8[off];
                }
            }
        }
    }
};

struct EpiDec8 {
    const float *bi, *bo, *bfv, *bg, *b1, *b2;
    ushort* c; u8* hn8; u8* hid1cur;
    const int* tokens; const int* len; int t;
    float* accs;
    __device__ void operator()(int bm, int bn, int wr, int wc, int lane,
                               f32x4 (&acc)[2][4]) const {
        const int rbase = bm + wr * 32 + ((lane >> 4) << 2);
        if (bn < 4096) {
            const int j = ((bn >> 6) + wc) * 16 + (lane & 15);
            const int kt = (j + 128) >> 6;
            const int kp = (j + 128) & 63;
            const size_t fo = frag_off(0, kp);
#pragma unroll
            for (int m = 0; m < 2; ++m) {
#pragma unroll
                for (int r = 0; r < 4; ++r) {
                    const int b = rbase + m * 16 + r;
                    const size_t o = (size_t)b * 1024 + j;
                    float gi = sigf(acc[m][0][r] + bi[j]);
                    float go = sigf(acc[m][1][r] + bo[j]);
                    float gf = sigf(acc[m][2][r] + bfv[j]);
                    float gg = tanhfast(acc[m][3][r] + bg[j]);
                    float nc = gf * bf2f(c[o]) + gi * gg;
                    c[o] = f2bf(nc);
                    const size_t off = ((size_t)(kt - 2) * 64 + (b >> 4)) * 1024 +
                                       fo + (size_t)(b & 15) * 16;
                    hn8[off] = f2e4(go * tanhfast(nc));
                }
            }
        } else if (bn < 5120) {
            const int cb = (bn - 4096) + wc * 64;
#pragma unroll
            for (int m = 0; m < 2; ++m)
#pragma unroll
                for (int n = 0; n < 4; ++n) {
                    const int col = cb + n * 16 + (lane & 15);
                    const int kt = col >> 6;
                    const size_t fo = frag_off(0, col & 63);
#pragma unroll
                    for (int r = 0; r < 4; ++r) {
                        const int row = rbase + m * 16 + r;
                        const size_t off = ((size_t)kt * 64 + (row >> 4)) * 1024 +
                                           fo + (size_t)(row & 15) * 16;
                        hid1cur[off] = f2e4(fmaxf(acc[m][n][r] + b1[col], 0.0f));
                    }
                }
        } else {
            if (wc != 0) return;
            const int ts = t - 1;
            const int col0 = lane & 15;
            const bool v1ok = col0 < (V_ - 16);
            const float b2v0 = b2[col0];
            const float b2v1 = v1ok ? b2[16 + col0] : 0.0f;
            float ce_loc = 0.f, cor_loc = 0.f, msk_loc = 0.f;
#pragma unroll
            for (int m = 0; m < 2; ++m) {
#pragma unroll
                for (int r = 0; r < 4; ++r) {
                    const int b = rbase + m * 16 + r;
                    const int lb = len[b];
                    float v0 = acc[m][0][r] + b2v0;
                    float v1 = v1ok ? (acc[m][1][r] + b2v1) : -1e30f;
                    float mv; int mi;
                    if (v1 > v0) { mv = v1; mi = 16 + col0; } else { mv = v0; mi = col0; }
#pragma unroll
                    for (int s = 1; s < 16; s <<= 1) {
                        float ov = __shfl_xor(mv, s);
                        int oi = __shfl_xor(mi, s);
                        if (ov > mv || (ov == mv && oi < mi)) { mv = ov; mi = oi; }
                    }
                    float se = expf(v0 - mv) + (v1ok ? expf(v1 - mv) : 0.0f);
#pragma unroll
                    for (int s = 1; s < 16; s <<= 1) se += __shfl_xor(se, s);
                    float lse = mv + logf(se);
                    int tgt = (ts < lb) ? tokens[b * T_ + ts] : 0;
                    int srcl = (lane & 48) | (tgt & 15);
                    float sv0 = __shfl(v0, srcl);
                    float sv1 = __shfl(v1, srcl);
                    float stgt = (tgt < 16) ? sv0 : sv1;
                    if (ts <= lb && col0 == 0) {
                        ce_loc += lse - stgt;
                        cor_loc += (mi == tgt) ? 1.0f : 0.0f;
                        msk_loc += 1.0f;
                    }
                }
            }
            float ce = __shfl(ce_loc, 0) + __shfl(ce_loc, 16) + __shfl(ce_loc, 32) + __shfl(ce_loc, 48);
            float co = __shfl(cor_loc, 0) + __shfl(cor_loc, 16) + __shfl(cor_loc, 32) + __shfl(cor_loc, 48);
            float mk = __shfl(msk_loc, 0) + __shfl(msk_loc, 16) + __shfl(msk_loc, 32) + __shfl(msk_loc, 48);
            if (lane == 0) {
                atomicAdd(&accs[0], ce);
                atomicAdd(&accs[1], co);
                atomicAdd(&accs[2], mk);
            }
        }
    }
};

struct EpiStoreF32 {
    float* out; int ldc;
    __device__ void operator()(int bm, int bn, int wr, int wc, int lane,
                               f32x4 (&acc)[2][4]) const {
        const int rbase = bm + wr * 32 + ((lane >> 4) << 2);
        const int cbase = bn + wc * 64 + (lane & 15);
#pragma unroll
        for (int m = 0; m < 2; ++m)
#pragma unroll
            for (int n = 0; n < 4; ++n)
#pragma unroll
                for (int r = 0; r < 4; ++r)
                    out[(size_t)(rbase + m * 16 + r) * ldc + cbase + n * 16] = acc[m][n][r];
    }
};
struct EpiBiasF8Frag {
    u8* out; const float* bias;
    __device__ void operator()(int bm, int bn, int wr, int wc, int lane,
                               f32x4 (&acc)[2][4]) const {
        const int rbase = bm + wr * 32 + ((lane >> 4) << 2);
        const int cbase = bn + wc * 64 + (lane & 15);
#pragma unroll
        for (int m = 0; m < 2; ++m)
#pragma unroll
            for (int n = 0; n < 4; ++n) {
                const int col = cbase + n * 16;
                const int kt = (col + 128) >> 6;
                const size_t fo = frag_off(0, col & 63);
#pragma unroll
                for (int r = 0; r < 4; ++r) {
                    const int row = rbase + m * 16 + r;
                    const size_t off = ((size_t)(kt - 2) * 64 + (row >> 4)) * 1024 +
                                       fo + (size_t)(row & 15) * 16;
                    out[off] = f2e4(acc[m][n][r] + bias[col]);
                }
            }
    }
};

// ================= MEGA-PACK: all prep work in ONE launch =================
struct PackP {
    const float *x_enc, *emb, *Wih_f, *Whh_f, *Wih_b, *Whh_b;
    const float *Wi, *Wo, *Wf, *Wg, *W1, *W2, *Wm, *Wl, *Wz;
    const int *tokens, *len;
    ushort *cenc, *cdec, *Wml, *Wzp;
    u8 *hfA, *xef, *xdf, *WfE, *WfDg, *WfD1, *WfD2;
    float* accs;
};

__global__ __launch_bounds__(256) void mega_pack(PackP P) {
    const int blk = blockIdx.x;
    const int tid = threadIdx.x;

    if (blk < 8192) {                                   // init_zero
        int i = blk * 256 + tid;
        if (i < 2 * 1024 * 1024) { P.cenc[i] = 0; P.hfA[i] = 0; }
        if (i < 1024 * 1024) P.cdec[i] = 0;
        if (i < 8) P.accs[i] = 0.0f;
        return;
    }
    if (blk < 17408) {                                  // pack_wenc_frag
        int i = (blk - 8192) * 256 + tid;
        int b0 = (i & 3) * 4;
        int lane = (i >> 2) & 63;
        int unit = i >> 8;
        int sub = unit & 7;
        int ktb = unit >> 3;
        int kt = ktb % 18;
        int blk2 = ktb / 18;
        int bnb = blk2 & 31, dir = blk2 >> 5;
        int col = bnb * 128 + (sub >> 2) * 64 + (sub & 3) * 16 + (lane & 15);
        int j = ((col >> 6) << 4) + (col & 15);
        int g = (col >> 4) & 3;
        int srow = g * 1024 + j;
        int k = kt * 64 + (b0 >> 3) * 32 + (lane >> 4) * 8 + (b0 & 7);
        float4 v;
        if (k < 128) {
            const float* s = dir ? P.Wih_b : P.Wih_f;
            v = *(const float4*)(s + (size_t)srow * 128 + k);
        } else {
            const float* s = dir ? P.Whh_b : P.Whh_f;
            v = *(const float4*)(s + (size_t)srow * 1024 + (k - 128));
        }
        unsigned o = f2e4(v.x) | ((unsigned)f2e4(v.y) << 8) |
                     ((unsigned)f2e4(v.z) << 16) | ((unsigned)f2e4(v.w) << 24);
        *(unsigned*)(P.WfE + (size_t)unit * 1024 + lane * 16 + b0) = o;
        return;
    }
    if (blk < 22016) {                                  // pack_wdec_frag
        int i = (blk - 17408) * 256 + tid;
        int b0 = (i & 3) * 4;
        int lane = (i >> 2) & 63;
        int unit = i >> 8;
        int sub = unit & 7;
        int ktb = unit >> 3;
        int kt = ktb % 18;
        int bnb = ktb / 18;
        int col = bnb * 128 + (sub >> 2) * 64 + (sub & 3) * 16 + (lane & 15);
        int j = ((col >> 6) << 4) + (col & 15);
        int g = (col >> 4) & 3;
        const float* s = (g == 0) ? P.Wi : (g == 1) ? P.Wo : (g == 2) ? P.Wf : P.Wg;
        int k = kt * 64 + (b0 >> 3) * 32 + (lane >> 4) * 8 + (b0 & 7);
        float4 v = *(const float4*)(s + (size_t)j * 1152 + k);
        unsigned o = f2e4(v.x) | ((unsigned)f2e4(v.y) << 8) |
                     ((unsigned)f2e4(v.z) << 16) | ((unsigned)f2e4(v.w) << 24);
        *(unsigned*)(P.WfDg + (size_t)unit * 1024 + lane * 16 + b0) = o;
        return;
    }
    if (blk < 23296) {                                  // pack_w1_frag
        int i = (blk - 22016) * 256 + tid;
        int b0 = (i & 3) * 4;
        int lane = (i >> 2) & 63;
        int unit = i >> 8;
        int sub = unit & 7;
        int ktb = unit >> 3;
        int kt = ktb % 20;
        int bnb = ktb / 20;
        int col = bnb * 128 + (sub >> 2) * 64 + (sub & 3) * 16 + (lane & 15);
        int k = kt * 64 + (b0 >> 3) * 32 + (lane >> 4) * 8 + (b0 & 7);
        float4 v = *(const float4*)(P.W1 + (size_t)col * 1280 + k);
        unsigned o = f2e4(v.x) | ((unsigned)f2e4(v.y) << 8) |
                     ((unsigned)f2e4(v.z) << 16) | ((unsigned)f2e4(v.w) << 24);
        *(unsigned*)(P.WfD1 + (size_t)unit * 1024 + lane * 16 + b0) = o;
        return;
    }
    if (blk < 23424) {                                  // pack_w2_frag
        int i = (blk - 23296) * 256 + tid;
        int b0 = (i & 3) * 4;
        int lane = (i >> 2) & 63;
        int unit = i >> 8;
        int sub = unit & 7;
        int kt = unit >> 3;
        int col = (sub >> 2) * 64 + (sub & 3) * 16 + (lane & 15);
        unsigned o = 0;
        if (col < V_) {
            int k = kt * 64 + (b0 >> 3) * 32 + (lane >> 4) * 8 + (b0 & 7);
            float4 v = *(const float4*)(P.W2 + (size_t)col * 1024 + k);
            o = f2e4(v.x) | ((unsigned)f2e4(v.y) << 8) |
                ((unsigned)f2e4(v.z) << 16) | ((unsigned)f2e4(v.w) << 24);
        }
        *(unsigned*)(P.WfD2 + (size_t)unit * 1024 + lane * 16 + b0) = o;
        return;
    }
    if (blk < 23680) {                                  // pack_cols Wm
        int i = (blk - 23424) * 256 + tid;
        int r = i >> 9, c4 = (i & 511) * 4;
        float4 v = *(const float4*)(P.Wm + (size_t)r * 2048 + c4);
        ushort4 o = { f2bf(v.x), f2bf(v.y), f2bf(v.z), f2bf(v.w) };
        *(ushort4*)(P.Wml + (size_t)r * 2048 + c4) = o;
        return;
    }
    if (blk < 23936) {                                  // pack_cols Wl
        int i = (blk - 23680) * 256 + tid;
        int r = i >> 9, c4 = (i & 511) * 4;
        float4 v = *(const float4*)(P.Wl + (size_t)r * 2048 + c4);
        ushort4 o = { f2bf(v.x), f2bf(v.y), f2bf(v.z), f2bf(v.w) };
        *(ushort4*)(P.Wml + (size_t)(r + 128) * 2048 + c4) = o;
        return;
    }
    if (blk < 24064) {                                  // pack_cols Wz
        int i = (blk - 23936) * 256 + tid;
        int r = i >> 5, c4 = (i & 31) * 4;
        float4 v = *(const float4*)(P.Wz + (size_t)r * 128 + c4);
        ushort4 o = { f2bf(v.x), f2bf(v.y), f2bf(v.z), f2bf(v.w) };
        *(ushort4*)(P.Wzp + (size_t)r * 128 + c4) = o;
        return;
    }
    if (blk < 27904) {                                  // pack_xenc_frag
        int i = (blk - 24064) * 256 + tid;
        int b0 = (i & 3) * 4;
        int lane = (i >> 2) & 63;
        int unit = i >> 8;
        int rg = unit & 127;
        int tk = unit >> 7;
        int kt = tk & 1, t = tk >> 1;
        int row = rg * 16 + (lane & 15);
        int k = kt * 64 + (b0 >> 3) * 32 + (lane >> 4) * 8 + (b0 & 7);
        int dir = row >> 10, bidx = row & 1023;
        int tt = t;
        if (dir) { int ri = P.len[bidx] - 1 - t; tt = ri < 0 ? 0 : (ri > T_ - 1 ? T_ - 1 : ri); }
        float4 v = *(const float4*)(P.x_enc + ((size_t)bidx * T_ + tt) * 128 + k);
        unsigned o = f2e4(v.x) | ((unsigned)f2e4(v.y) << 8) |
                     ((unsigned)f2e4(v.z) << 16) | ((unsigned)f2e4(v.w) << 24);
        *(unsigned*)(P.xef + (size_t)unit * 1024 + lane * 16 + b0) = o;
        return;
    }
    {                                                   // pack_xdec_frag
        int i = (blk - 27904) * 256 + tid;
        int b0 = (i & 3) * 4;
        int lane = (i >> 2) & 63;
        int unit = i >> 8;
        int rg = unit & 63;
        int tk = unit >> 6;
        int kt = tk & 1, t = tk >> 1;
        unsigned o = 0;
        if (t > 0) {
            int row = rg * 16 + (lane & 15);
            int k = kt * 64 + (b0 >> 3) * 32 + (lane >> 4) * 8 + (b0 & 7);
            int tok = P.tokens[(size_t)row * T_ + (t - 1)];
            float4 v = *(const float4*)(P.emb + (size_t)tok * 128 + k);
            o = f2e4(v.x) | ((unsigned)f2e4(v.y) << 8) |
                ((unsigned)f2e4(v.z) << 16) | ((unsigned)f2e4(v.w) << 24);
        }
        *(unsigned*)(P.xdf + (size_t)unit * 1024 + lane * 16 + b0) = o;
    }
}

// ================= elementwise =================
__global__ void latent_ew(const float* __restrict__ ml, const float* __restrict__ bmv,
                          const float* __restrict__ blv, const float* __restrict__ eps,
                          ushort* __restrict__ zb, u8* __restrict__ z8f,
                          float* __restrict__ klacc) {
    int idx = blockIdx.x * 256 + threadIdx.x;
    int b = idx >> 7, l = idx & (L_ - 1);
    float mean = ml[(size_t)b * 256 + l] + bmv[l];
    float logv = ml[(size_t)b * 256 + L_ + l] + blv[l];
    float zv = eps[idx] * expf(0.5f * logv) + mean;
    zb[idx] = f2bf(zv);
    size_t off = ((size_t)(l >> 6) * 64 + (b >> 4)) * 1024 +
                 frag_off(0, l & 63) + (size_t)(b & 15) * 16;
    z8f[off] = f2e4(zv);
    float part = 1.0f + logv - mean * mean - expf(logv);
    for (int offc = 32; offc; offc >>= 1) part += __shfl_down(part, offc);
    __shared__ float s[4];
    int lane = threadIdx.x & 63, wv = threadIdx.x >> 6;
    if (lane == 0) s[wv] = part;
    __syncthreads();
    if (threadIdx.x == 0) atomicAdd(klacc, s[0] + s[1] + s[2] + s[3]);
}

__global__ void finalize_k(const float* accs, float* out) {
    if (threadIdx.x == 0 && blockIdx.x == 0) {
        float kl = -0.5f * accs[3] / (float)B_;
        float amino = accs[0] / (float)B_;
        out[0] = amino + 0.1f * kl;
        out[1] = amino;
        out[2] = kl;
        out[3] = accs[1] / accs[2];
    }
}

// ================= host =================
extern "C" void kernel_launch(void* const* d_in, const int* in_sizes, int n_in,
                              void* d_out, int out_size, void* d_ws, size_t ws_size,
                              hipStream_t stream) {
    (void)in_sizes; (void)n_in; (void)out_size; (void)ws_size;
    const float* x_enc  = (const float*)d_in[0];
    const int*   tokens = (const int*)d_in[1];
    const int*   lengths= (const int*)d_in[2];
    const float* eps    = (const float*)d_in[3];
    const float* emb    = (const float*)d_in[4];
    const float* Wih_f  = (const float*)d_in[5];
    const float* Whh_f  = (const float*)d_in[6];
    const float* b_f    = (const float*)d_in[7];
    const float* Wih_b  = (const float*)d_in[8];
    const float* Whh_b  = (const float*)d_in[9];
    const float* b_b    = (const float*)d_in[10];
    const float* Wm     = (const float*)d_in[11];
    const float* bm     = (const float*)d_in[12];
    const float* Wl     = (const float*)d_in[13];
    const float* bl     = (const float*)d_in[14];
    const float* Wz     = (const float*)d_in[15];
    const float* bz     = (const float*)d_in[16];
    const float* Wi     = (const float*)d_in[17];
    const float* bi     = (const float*)d_in[18];
    const float* Wo     = (const float*)d_in[19];
    const float* bo     = (const float*)d_in[20];
    const float* Wfm    = (const float*)d_in[21];
    const float* bf     = (const float*)d_in[22];
    const float* Wg     = (const float*)d_in[23];
    const float* bg     = (const float*)d_in[24];
    const float* W1     = (const float*)d_in[25];
    const float* b1     = (const float*)d_in[26];
    const float* W2     = (const float*)d_in[27];
    const float* b2     = (const float*)d_in[28];

    float*  ml   = (float*)d_ws;
    float*  accs = ml + 262144;
    ushort* cenc = (ushort*)(accs + 64);
    ushort* cdec = cenc + 2 * 1024 * 1024;
    ushort* hidp = cdec + 1024 * 1024;
    ushort* Wml  = hidp + 2 * 1024 * 1024;
    ushort* Wzp  = Wml + 256 * 2048;
    ushort* zb   = Wzp + 1024 * 128;
    u8* xef  = (u8*)(zb + 1024 * 128);
    u8* hfA  = xef + 15 * 2 * 128 * 1024;
    u8* hfB  = hfA + 16 * 128 * 1024;
    u8* xdf  = hfB + 16 * 128 * 1024;
    u8* hdfA = xdf + 15 * 2 * 64 * 1024;
    u8* hdfB = hdfA + 16 * 64 * 1024;
    u8* z8f  = hdfB + 16 * 64 * 1024;
    u8* h1fA = z8f + 2 * 64 * 1024;
    u8* h1fB = h1fA + 16 * 64 * 1024;
    u8* WfE  = h1fB + 16 * 64 * 1024;
    u8* WfDg = WfE + 2 * 32 * 18 * 8 * 1024;
    u8* WfD1 = WfDg + 32 * 18 * 8 * 1024;
    u8* WfD2 = WfD1 + 8 * 20 * 8 * 1024;

    // ---- ALL prep in one launch ----
    {
        PackP p{ x_enc, emb, Wih_f, Whh_f, Wih_b, Whh_b,
                 Wi, Wo, Wfm, Wg, W1, W2, Wm, Wl, Wz,
                 tokens, lengths,
                 cenc, cdec, Wml, Wzp,
                 hfA, xef, xdf, WfE, WfDg, WfD1, WfD2, accs };
        mega_pack<<<29824, 256, 0, stream>>>(p);
    }

    // ---- encoder: fp8 reg-direct 64x128 ring-3 + XCD swizzle ----
    {
        const u8* hc = hfA; u8* hn = hfB;
        for (int t = 0; t < T_; ++t) {
            gemm_reg<<<dim3(32, 32), 256, 0, stream>>>(
                AEnc{ xef + (size_t)t * 2 * 131072, hc, 0 }, WEnc{ WfE },
                EpiEnc8{ b_f, b_b, lengths, t, cenc, hc, hn, hidp });
            const u8* tmp = hn; hn = (u8*)hc; hc = tmp;
        }
    }
    // ---- latents (bf16 LDS path) ----
    gemm_t64<<<dim3(2, 16), 256, 0, stream>>>(
        ALdPlain{ hidp, 2048, 2048 }, WLdPlain{ Wml, 2048 }, EpiStoreF32{ ml, 256 });
    latent_ew<<<512, 256, 0, stream>>>(ml, bm, bl, eps, zb, z8f, &accs[3]);
    gemm_t64<<<dim3(8, 16), 256, 0, stream>>>(
        ALdPlain{ zb, 128, 128 }, WLdPlain{ Wzp, 128 }, EpiBiasF8Frag{ hdfA, bz });

    // ---- decoder: fp8 reg-direct 64x128 ring-3 + XCD swizzle ----
    {
        const u8* dc = hdfA; u8* dn = hdfB;
        for (int t = 0; t < T_; ++t) {
            u8* h1c = (t & 1) ? h1fB : h1fA;
            const u8* h1p = (t & 1) ? h1fA : h1fB;
            dim3 grid(t == 0 ? 40 : 41, 16);
            gemm_reg<<<grid, 256, 0, stream>>>(
                ADec{ xdf + (size_t)t * 2 * 65536, dc, z8f, h1p, 0 },
                WDec{ WfDg, WfD1, WfD2 },
                EpiDec8{ bi, bo, bf, bg, b1, b2, cdec, dn, h1c, tokens, lengths, t, accs });
            const u8* tmp = dn; dn = (u8*)dc; dc = tmp;
        }
        gemm_reg<<<dim3(1, 16), 256, 0, stream>>>(
            ADec{ xdf, dc, z8f, h1fA, 5120 },
            WDec{ WfDg, WfD1, WfD2 },
            EpiDec8{ bi, bo, bf, bg, b1, b2, cdec, hdfB, h1fB, tokens, lengths, T_, accs });
    }

    finalize_k<<<1, 64, 0, stream>>>(accs, (float*)d_out);
}